// Round 1
// baseline (394.060 us; speedup 1.0000x reference)
//
#include <hip/hip_runtime.h>

// LSTM cell: gates = [x|h] @ [Wx|Wh]^T + b  -> sigmoid/tanh elementwise.
// fp32 inputs; GEMM done via bf16 MFMA with hi/lo split (3 terms) for ~fp32 accuracy.
// Pipeline: convert (fp32 -> bf16 hi/lo in ws) -> gemm (m97-style 128^2 tile) -> epilogue.

typedef __attribute__((ext_vector_type(4))) float  f32x4;
typedef __attribute__((ext_vector_type(8))) __bf16 bf16x8;
typedef __attribute__((ext_vector_type(4))) short  s16x4;

#define HID    1024
#define BATCH  4096
#define KDIM   2048   // concatenated x|h along k
#define NDIM   4096   // 4 gates * HID

// ---------------- fp32 <-> bf16 helpers (manual, round-to-nearest-even) ----------------
__device__ __forceinline__ unsigned short f2bf(float f) {
  unsigned u = __builtin_bit_cast(unsigned, f);
  u += 0x7FFFu + ((u >> 16) & 1u);
  return (unsigned short)(u >> 16);
}
__device__ __forceinline__ float bf2f(unsigned short s) {
  return __builtin_bit_cast(float, (unsigned)s << 16);
}

// ---------------- 1) convert: build A(hi/lo)[4096][2048], B(hi/lo)[4096][2048] ----------------
// grid: 8192 blocks x 256 thr. Block = one row (batch row for A, gate-major n for B).
__global__ void convert_kernel(
    const float* __restrict__ x,   const float* __restrict__ h,
    const float* __restrict__ Wix, const float* __restrict__ Wfx,
    const float* __restrict__ Wox, const float* __restrict__ Wcx,
    const float* __restrict__ Wih, const float* __restrict__ Wfh,
    const float* __restrict__ Woh, const float* __restrict__ Wch,
    short* __restrict__ Ahi, short* __restrict__ Alo,
    short* __restrict__ Bhi, short* __restrict__ Blo)
{
  const int row = blockIdx.x;   // 0..8191
  const int tid = threadIdx.x;  // 0..255, one float4 per half-row
  const float *s0, *s1;
  short *ohi, *olo;
  if (row < BATCH) {
    s0  = x + (size_t)row * 1024;
    s1  = h + (size_t)row * 1024;
    ohi = Ahi + (size_t)row * KDIM;
    olo = Alo + (size_t)row * KDIM;
  } else {
    const int n = row - BATCH;          // 0..4095, gate-major
    const int g = n >> 10, j = n & 1023; // g: 0=i 1=f 2=o 3=c
    const float* wx = (g == 0) ? Wix : (g == 1) ? Wfx : (g == 2) ? Wox : Wcx;
    const float* wh = (g == 0) ? Wih : (g == 1) ? Wfh : (g == 2) ? Woh : Wch;
    s0  = wx + (size_t)j * 1024;
    s1  = wh + (size_t)j * 1024;
    ohi = Bhi + (size_t)n * KDIM;
    olo = Blo + (size_t)n * KDIM;
  }
  f32x4 v0 = ((const f32x4*)s0)[tid];   // k = tid*4 .. +3   (< 1024)
  f32x4 v1 = ((const f32x4*)s1)[tid];   // k = 1024 + tid*4 ..
  s16x4 h0, l0, h1, l1;
  #pragma unroll
  for (int e = 0; e < 4; ++e) {
    unsigned short a = f2bf(v0[e]);
    h0[e] = (short)a; l0[e] = (short)f2bf(v0[e] - bf2f(a));
    unsigned short b = f2bf(v1[e]);
    h1[e] = (short)b; l1[e] = (short)f2bf(v1[e] - bf2f(b));
  }
  ((s16x4*)ohi)[tid]          = h0;
  ((s16x4*)olo)[tid]          = l0;
  ((s16x4*)(ohi + 1024))[tid] = h1;
  ((s16x4*)(olo + 1024))[tid] = l1;
}

// ---------------- 2) GEMM: gates[4096][4096] fp32, 128x128 tile, BK=32 ----------------
// m97 structure: single-buffer LDS, global_load_lds width=16 staging, 2 barriers/k-step.
// hi/lo split: 3 MFMAs per fragment pair (hh + hl + lh), all into the same fp32 acc.
#define GLD16(SRC, DST) \
  __builtin_amdgcn_global_load_lds((const __attribute__((address_space(1))) void*)(SRC), \
                                   (__attribute__((address_space(3))) void*)(DST), 16, 0, 0)

__global__ __launch_bounds__(256, 2) void gemm_gates_kernel(
    const short* __restrict__ Ahi, const short* __restrict__ Alo,
    const short* __restrict__ Bhi, const short* __restrict__ Blo,
    float* __restrict__ gates)
{
  // LDS: 4 tiles of [128][32] bf16 (8KB each): Ahi, Alo, Bhi, Blo
  __shared__ short lds[4 * 4096];
  const int tid  = threadIdx.x;
  const int wave = tid >> 6;
  const int lane = tid & 63;
  const int m0 = blockIdx.y * 128;
  const int n0 = blockIdx.x * 128;
  const int wr = (wave >> 1) * 64;   // wave row offset within tile
  const int wc = (wave & 1) * 64;    // wave col offset

  f32x4 acc[4][4];
  #pragma unroll
  for (int i = 0; i < 4; ++i)
    #pragma unroll
    for (int j = 0; j < 4; ++j)
      acc[i][j] = (f32x4){0.f, 0.f, 0.f, 0.f};

  const int srow = lane >> 2;        // staging: row-in-chunk 0..15
  const int scol = (lane & 3) * 8;   // staging: k element offset

  for (int kt = 0; kt < KDIM / 32; ++kt) {
    const int k0 = kt * 32;
    // ---- stage 4 tiles; each wave covers chunks (wave*2, wave*2+1) of 16 rows each ----
    #pragma unroll
    for (int i = 0; i < 2; ++i) {
      const int t   = wave * 2 + i;       // 0..7
      const int row = t * 16 + srow;      // 0..127
      const size_t aoff = (size_t)(m0 + row) * KDIM + k0 + scol;
      const size_t boff = (size_t)(n0 + row) * KDIM + k0 + scol;
      GLD16(Ahi + aoff, &lds[0 * 4096 + t * 512]);
      GLD16(Alo + aoff, &lds[1 * 4096 + t * 512]);
      GLD16(Bhi + boff, &lds[2 * 4096 + t * 512]);
      GLD16(Blo + boff, &lds[3 * 4096 + t * 512]);
    }
    __syncthreads();   // compiler drains vmcnt before s_barrier

    // ---- fragments: lane l -> row l&15, k = (l>>4)*8 .. +7 (16B contiguous) ----
    const int frow = lane & 15;
    const int kg8  = (lane >> 4) * 8;
    bf16x8 ah[4], al[4], bh[4], bl[4];
    #pragma unroll
    for (int f = 0; f < 4; ++f) {
      const int ra = (wr + f * 16 + frow) * 32 + kg8;
      ah[f] = *(const bf16x8*)&lds[0 * 4096 + ra];
      al[f] = *(const bf16x8*)&lds[1 * 4096 + ra];
      const int rb = (wc + f * 16 + frow) * 32 + kg8;
      bh[f] = *(const bf16x8*)&lds[2 * 4096 + rb];
      bl[f] = *(const bf16x8*)&lds[3 * 4096 + rb];
    }
    #pragma unroll
    for (int fm = 0; fm < 4; ++fm)
      #pragma unroll
      for (int fn = 0; fn < 4; ++fn) {
        acc[fm][fn] = __builtin_amdgcn_mfma_f32_16x16x32_bf16(ah[fm], bh[fn], acc[fm][fn], 0, 0, 0);
        acc[fm][fn] = __builtin_amdgcn_mfma_f32_16x16x32_bf16(ah[fm], bl[fn], acc[fm][fn], 0, 0, 0);
        acc[fm][fn] = __builtin_amdgcn_mfma_f32_16x16x32_bf16(al[fm], bh[fn], acc[fm][fn], 0, 0, 0);
      }
    __syncthreads();
  }

  // ---- C write: col = lane&15, row = (lane>>4)*4 + reg  [m89-verified layout] ----
  const int crow = m0 + wr + ((lane >> 4) << 2);
  const int ccol = n0 + wc + (lane & 15);
  #pragma unroll
  for (int fm = 0; fm < 4; ++fm)
    #pragma unroll
    for (int fn = 0; fn < 4; ++fn)
      #pragma unroll
      for (int r = 0; r < 4; ++r)
        gates[(size_t)(crow + fm * 16 + r) * NDIM + (ccol + fn * 16)] = acc[fm][fn][r];
}

// ---------------- 3) epilogue: bias + sigmoid/tanh + c/h ----------------
__device__ __forceinline__ float sigmoid_f(float v) { return 1.f / (1.f + __expf(-v)); }
__device__ __forceinline__ float tanh_f(float v) {
  float t = __expf(-2.f * fabsf(v));
  float r = (1.f - t) / (1.f + t);
  return copysignf(r, v);
}

__global__ void lstm_epilogue_kernel(
    const float* __restrict__ gates, const float* __restrict__ c1,
    const float* __restrict__ bix, const float* __restrict__ bih,
    const float* __restrict__ bfx, const float* __restrict__ bfh,
    const float* __restrict__ box, const float* __restrict__ boh,
    const float* __restrict__ bcx, const float* __restrict__ bch,
    float* __restrict__ out)
{
  const int m  = blockIdx.x;    // 0..4095 (one batch row per block)
  const int j4 = threadIdx.x;   // 0..255
  const int j  = j4 * 4;
  const f32x4* g = (const f32x4*)(gates + (size_t)m * NDIM);
  f32x4 gi = g[j4], gf = g[256 + j4], go = g[512 + j4], gc = g[768 + j4];
  const f32x4 vbi = *(const f32x4*)(bix + j) + *(const f32x4*)(bih + j);
  const f32x4 vbf = *(const f32x4*)(bfx + j) + *(const f32x4*)(bfh + j);
  const f32x4 vbo = *(const f32x4*)(box + j) + *(const f32x4*)(boh + j);
  const f32x4 vbc = *(const f32x4*)(bcx + j) + *(const f32x4*)(bch + j);
  const f32x4 vc1 = *(const f32x4*)(c1 + (size_t)m * HID + j);
  f32x4 hv, cv;
  #pragma unroll
  for (int e = 0; e < 4; ++e) {
    float I  = sigmoid_f(gi[e] + vbi[e]);
    float F  = sigmoid_f(gf[e] + vbf[e]);
    float O  = sigmoid_f(go[e] + vbo[e]);
    float Ct = tanh_f(gc[e] + vbc[e]);
    float cc = F * vc1[e] + I * Ct;
    cv[e] = cc;
    hv[e] = O * tanh_f(cc);
  }
  *(f32x4*)(out + (size_t)m * HID + j)                        = hv;   // h
  *(f32x4*)(out + (size_t)BATCH * HID + (size_t)m * HID + j)  = cv;   // c
}

// ---------------- launch ----------------
extern "C" void kernel_launch(void* const* d_in, const int* in_sizes, int n_in,
                              void* d_out, int out_size, void* d_ws, size_t ws_size,
                              hipStream_t stream) {
  const float* x    = (const float*)d_in[0];
  const float* h1   = (const float*)d_in[1];
  const float* c1   = (const float*)d_in[2];
  const float* W_ix = (const float*)d_in[3];  const float* b_ix = (const float*)d_in[4];
  const float* W_ih = (const float*)d_in[5];  const float* b_ih = (const float*)d_in[6];
  const float* W_fx = (const float*)d_in[7];  const float* b_fx = (const float*)d_in[8];
  const float* W_fh = (const float*)d_in[9];  const float* b_fh = (const float*)d_in[10];
  const float* W_ox = (const float*)d_in[11]; const float* b_ox = (const float*)d_in[12];
  const float* W_oh = (const float*)d_in[13]; const float* b_oh = (const float*)d_in[14];
  const float* W_cx = (const float*)d_in[15]; const float* b_cx = (const float*)d_in[16];
  const float* W_ch = (const float*)d_in[17]; const float* b_ch = (const float*)d_in[18];

  // ws layout: Ahi | Alo | Bhi | Blo (bf16, 16MB each) | gates (fp32, 64MB) = 128MB
  short* Ahi = (short*)d_ws;
  short* Alo = Ahi + (size_t)8 * 1024 * 1024;
  short* Bhi = Alo + (size_t)8 * 1024 * 1024;
  short* Blo = Bhi + (size_t)8 * 1024 * 1024;
  float* gates = (float*)(Blo + (size_t)8 * 1024 * 1024);

  convert_kernel<<<8192, 256, 0, stream>>>(x, h1,
      W_ix, W_fx, W_ox, W_cx, W_ih, W_fh, W_oh, W_ch,
      Ahi, Alo, Bhi, Blo);

  gemm_gates_kernel<<<dim3(32, 32), 256, 0, stream>>>(Ahi, Alo, Bhi, Blo, gates);

  lstm_epilogue_kernel<<<4096, 256, 0, stream>>>(gates, c1,
      b_ix, b_ih, b_fx, b_fh, b_ox, b_oh, b_cx, b_ch,
      (float*)d_out);
}

// Round 2
// 330.381 us; speedup vs baseline: 1.1927x; 1.1927x over previous
//
#include <hip/hip_runtime.h>

// LSTM cell: gates = [x|h] @ [Wx|Wh]^T + b -> sigmoid/tanh elementwise.
// fp32 inputs; GEMM via bf16 MFMA hi/lo split (3 terms: hh+hl+lh).
// Round 2: conflict-free plane LDS layout (pre-tiled in ws by convert),
//          2-phase prefetch (dbuf LDS, 1 barrier/kstep), epilogue fused into GEMM
//          via gate-interleaved B ordering (n' = 4*j + gate).

typedef __attribute__((ext_vector_type(4))) float  f32x4;
typedef __attribute__((ext_vector_type(8))) __bf16 bf16x8;
typedef __attribute__((ext_vector_type(8))) short  s16x8;

#define HID    1024
#define BATCH  4096
#define KDIM   2048
#define NDIM   4096
#define PANEL_STRIDE (128 * KDIM)   // 262144 elems per 128-row panel
#define KT_STRIDE    4096           // elems per (panel,kt) chunk: 4 g * 128 r * 8 e

// ---------------- fp32 <-> bf16 (round-to-nearest-even) ----------------
__device__ __forceinline__ unsigned short f2bf(float f) {
  unsigned u = __builtin_bit_cast(unsigned, f);
  u += 0x7FFFu + ((u >> 16) & 1u);
  return (unsigned short)(u >> 16);
}
__device__ __forceinline__ float bf2f(unsigned short s) {
  return __builtin_bit_cast(float, (unsigned)s << 16);
}

// ---------------- 1) convert: fp32 -> hi/lo bf16 in plane-tiled layout ----------------
// ws element (panel p, kt, g, r, e)  <=>  matrix (row = p*128+r, k = kt*32 + g*8 + e)
// A rows = batch rows; B rows n' = 4*j + gate (gate-interleaved), gate order i,f,o,c.
// grid: 4096 blocks (2048 A + 2048 B) x 256 thr. Block=(p,kt): thread t: r=t>>1, kh=t&1.
__global__ void convert_kernel(
    const float* __restrict__ x,   const float* __restrict__ h,
    const float* __restrict__ Wix, const float* __restrict__ Wfx,
    const float* __restrict__ Wox, const float* __restrict__ Wcx,
    const float* __restrict__ Wih, const float* __restrict__ Wfh,
    const float* __restrict__ Woh, const float* __restrict__ Wch,
    const float* __restrict__ bix, const float* __restrict__ bfx,
    const float* __restrict__ box, const float* __restrict__ bcx,
    const float* __restrict__ bih, const float* __restrict__ bfh,
    const float* __restrict__ boh, const float* __restrict__ bch,
    short* __restrict__ Ahi, short* __restrict__ Alo,
    short* __restrict__ Bhi, short* __restrict__ Blo,
    float* __restrict__ bias)
{
  const int bid = blockIdx.x;
  const int t   = threadIdx.x;
  const int r   = t >> 1;
  const int kh  = t & 1;
  const bool isA = bid < 2048;
  const int p  = isA ? (bid >> 6) : ((bid - 2048) >> 6);
  const int kt = bid & 63;
  const int kk = kt * 32 + kh * 16;   // absolute k of first of 16 elements (16-aligned,
                                      // never straddles the 1024 x|h boundary)
  const float* srow;
  short *dhi, *dlo;
  if (isA) {
    const int m = p * 128 + r;
    srow = (kk < 1024) ? (x + (size_t)m * 1024 + kk)
                       : (h + (size_t)m * 1024 + (kk - 1024));
    dhi = Ahi; dlo = Alo;
  } else {
    const int np = p * 128 + r;           // n' = 4*j + gate
    const int j = np >> 2, gate = np & 3;
    const float* wx = (gate == 0) ? Wix : (gate == 1) ? Wfx : (gate == 2) ? Wox : Wcx;
    const float* wh = (gate == 0) ? Wih : (gate == 1) ? Wfh : (gate == 2) ? Woh : Wch;
    srow = (kk < 1024) ? (wx + (size_t)j * 1024 + kk)
                       : (wh + (size_t)j * 1024 + (kk - 1024));
    dhi = Bhi; dlo = Blo;
    if (kt == 0 && t < 128) {             // combined bias in n' order
      const int np2 = p * 128 + t;
      const int j2 = np2 >> 2, g2 = np2 & 3;
      const float* bx  = (g2 == 0) ? bix : (g2 == 1) ? bfx : (g2 == 2) ? box : bcx;
      const float* bh2 = (g2 == 0) ? bih : (g2 == 1) ? bfh : (g2 == 2) ? boh : bch;
      bias[np2] = bx[j2] + bh2[j2];
    }
  }
  f32x4 v0 = ((const f32x4*)srow)[0];
  f32x4 v1 = ((const f32x4*)srow)[1];
  f32x4 v2 = ((const f32x4*)srow)[2];
  f32x4 v3 = ((const f32x4*)srow)[3];
  s16x8 hA, lA, hB, lB;
  #pragma unroll
  for (int c = 0; c < 8; ++c) {
    float fa = (c < 4) ? v0[c & 3] : v1[c & 3];
    unsigned short a = f2bf(fa);
    hA[c] = (short)a; lA[c] = (short)f2bf(fa - bf2f(a));
    float fb = (c < 4) ? v2[c & 3] : v3[c & 3];
    unsigned short b = f2bf(fb);
    hB[c] = (short)b; lB[c] = (short)f2bf(fb - bf2f(b));
  }
  const size_t base = ((size_t)p * 64 + kt) * KT_STRIDE;
  const int g0 = kh * 2;
  short* o = dhi + base + g0 * 1024 + r * 8;
  *(s16x8*)o = hA; *(s16x8*)(o + 1024) = hB;
  o = dlo + base + g0 * 1024 + r * 8;
  *(s16x8*)o = lA; *(s16x8*)(o + 1024) = lB;
}

// ---------------- 2) fused GEMM + LSTM epilogue ----------------
#define GLD16(SRC, DST) \
  __builtin_amdgcn_global_load_lds((const __attribute__((address_space(1))) void*)(SRC), \
                                   (__attribute__((address_space(3))) void*)(DST), 16, 0, 0)

__device__ __forceinline__ float sigmoid_f(float v) { return 1.f / (1.f + __expf(-v)); }
__device__ __forceinline__ float tanh_f(float v) {
  float t = __expf(-2.f * fabsf(v));
  float r = (1.f - t) / (1.f + t);
  return copysignf(r, v);
}

__global__ __launch_bounds__(256, 2) void gemm_fused_kernel(
    const short* __restrict__ Ahi, const short* __restrict__ Alo,
    const short* __restrict__ Bhi, const short* __restrict__ Blo,
    const float* __restrict__ bias, const float* __restrict__ c1,
    float* __restrict__ out)
{
  // 64KB LDS: k-loop uses 2 x 32KB buffers [Ahi|Alo|Bhi|Blo] (4096 shorts each);
  // after the loop the whole 64KB is reused as a 128x128 fp32 gates tile.
  __shared__ __align__(16) char smem[65536];
  short* sA = (short*)smem;
  float* gt = (float*)smem;

  const int tid = threadIdx.x, wave = tid >> 6, lane = tid & 63;
  int bid = blockIdx.x;
  bid = (bid & 7) * 128 + (bid >> 3);          // XCD-aware swizzle (1024 % 8 == 0)
  const int by = bid >> 5, bx = bid & 31;
  const int m0 = by * 128, n0 = bx * 128;
  const int wr = (wave >> 1) * 64, wc = (wave & 1) * 64;

  const short* pAh = Ahi + (size_t)by * PANEL_STRIDE;
  const short* pAl = Alo + (size_t)by * PANEL_STRIDE;
  const short* pBh = Bhi + (size_t)bx * PANEL_STRIDE;
  const short* pBl = Blo + (size_t)bx * PANEL_STRIDE;

  f32x4 acc[4][4];
  #pragma unroll
  for (int i = 0; i < 4; ++i)
    #pragma unroll
    for (int j = 0; j < 4; ++j)
      acc[i][j] = (f32x4){0.f, 0.f, 0.f, 0.f};

  const int c0   = wave * 2;     // this wave's 2 staging chunks
  const int loff = lane * 8;     // contiguous 16B per lane within chunk

  // stage(buf, kt): ws chunk is contiguous (4096 elems) -> 8 x GLD16 per array
  #define STAGE(BUF, KT) do {                                            \
    const size_t koff = (size_t)(KT) * KT_STRIDE;                        \
    const int sb = (BUF) * 16384;                                        \
    _Pragma("unroll")                                                    \
    for (int i_ = 0; i_ < 2; ++i_) {                                     \
      const int c_ = c0 + i_;                                            \
      GLD16(pAh + koff + c_ * 512 + loff, &sA[sb + c_ * 512]);           \
      GLD16(pAl + koff + c_ * 512 + loff, &sA[sb + 4096  + c_ * 512]);   \
      GLD16(pBh + koff + c_ * 512 + loff, &sA[sb + 8192  + c_ * 512]);   \
      GLD16(pBl + koff + c_ * 512 + loff, &sA[sb + 12288 + c_ * 512]);   \
    }                                                                    \
  } while (0)

  STAGE(0, 0);
  __syncthreads();   // drain prologue loads

  const int g = lane >> 4, frow = lane & 15;
  for (int kt = 0; kt < 64; ++kt) {
    const int cur = kt & 1;
    if (kt < 63) STAGE(cur ^ 1, kt + 1);   // prefetch overlaps this tile's MFMA
    const int sb = cur * 16384;
    bf16x8 ah[4], al[4], bh[4], bl[4];
    #pragma unroll
    for (int f = 0; f < 4; ++f) {
      const int ra = g * 1024 + (wr + f * 16 + frow) * 8;   // plane layout: conflict-free
      ah[f] = *(const bf16x8*)&sA[sb + ra];
      al[f] = *(const bf16x8*)&sA[sb + 4096 + ra];
      const int rb = g * 1024 + (wc + f * 16 + frow) * 8;
      bh[f] = *(const bf16x8*)&sA[sb + 8192 + rb];
      bl[f] = *(const bf16x8*)&sA[sb + 12288 + rb];
    }
    #pragma unroll
    for (int fm = 0; fm < 4; ++fm)
      #pragma unroll
      for (int fn = 0; fn < 4; ++fn) {
        acc[fm][fn] = __builtin_amdgcn_mfma_f32_16x16x32_bf16(ah[fm], bh[fn], acc[fm][fn], 0, 0, 0);
        acc[fm][fn] = __builtin_amdgcn_mfma_f32_16x16x32_bf16(ah[fm], bl[fn], acc[fm][fn], 0, 0, 0);
        acc[fm][fn] = __builtin_amdgcn_mfma_f32_16x16x32_bf16(al[fm], bh[fn], acc[fm][fn], 0, 0, 0);
      }
    __syncthreads();   // next-tile loads done + all waves done reading cur
  }

  // ---- dump acc into LDS gates tile [128][128] fp32 ----
  // C layout: col = lane&15, row = (lane>>4)*4 + reg  [m89-verified]
  const int lr0 = wr + ((lane >> 4) << 2);
  const int lc0 = wc + (lane & 15);
  #pragma unroll
  for (int fm = 0; fm < 4; ++fm)
    #pragma unroll
    for (int fn = 0; fn < 4; ++fn)
      #pragma unroll
      for (int rr = 0; rr < 4; ++rr)
        gt[(lr0 + fm * 16 + rr) * 128 + (lc0 + fn * 16)] = acc[fm][fn][rr];
  __syncthreads();

  // ---- fused epilogue: cols 4*jj+{0,1,2,3} = gates i,f,o,c of j = n0/4 + jj ----
  const int j0 = n0 >> 2;
  #pragma unroll
  for (int it = 0; it < 16; ++it) {
    const int idx = it * 256 + tid;
    const int row = idx >> 5, jj = idx & 31;
    f32x4 gv = *(const f32x4*)&gt[row * 128 + jj * 4];
    f32x4 bv = *(const f32x4*)&bias[n0 + jj * 4];
    const int m = m0 + row, jg = j0 + jj;
    const float c1v = c1[(size_t)m * HID + jg];
    const float I  = sigmoid_f(gv[0] + bv[0]);
    const float F  = sigmoid_f(gv[1] + bv[1]);
    const float O  = sigmoid_f(gv[2] + bv[2]);
    const float Ct = tanh_f(gv[3] + bv[3]);
    const float cc = F * c1v + I * Ct;
    out[(size_t)m * HID + jg]                         = O * tanh_f(cc);  // h
    out[(size_t)BATCH * HID + (size_t)m * HID + jg]   = cc;              // c
  }
  #undef STAGE
}

// ---------------- launch ----------------
extern "C" void kernel_launch(void* const* d_in, const int* in_sizes, int n_in,
                              void* d_out, int out_size, void* d_ws, size_t ws_size,
                              hipStream_t stream) {
  const float* x    = (const float*)d_in[0];
  const float* h1   = (const float*)d_in[1];
  const float* c1   = (const float*)d_in[2];
  const float* W_ix = (const float*)d_in[3];  const float* b_ix = (const float*)d_in[4];
  const float* W_ih = (const float*)d_in[5];  const float* b_ih = (const float*)d_in[6];
  const float* W_fx = (const float*)d_in[7];  const float* b_fx = (const float*)d_in[8];
  const float* W_fh = (const float*)d_in[9];  const float* b_fh = (const float*)d_in[10];
  const float* W_ox = (const float*)d_in[11]; const float* b_ox = (const float*)d_in[12];
  const float* W_oh = (const float*)d_in[13]; const float* b_oh = (const float*)d_in[14];
  const float* W_cx = (const float*)d_in[15]; const float* b_cx = (const float*)d_in[16];
  const float* W_ch = (const float*)d_in[17]; const float* b_ch = (const float*)d_in[18];

  // ws: Ahi | Alo | Bhi | Blo (16MB each, plane-tiled) | bias_sum (16KB)
  short* Ahi = (short*)d_ws;
  short* Alo = Ahi + (size_t)8 * 1024 * 1024;
  short* Bhi = Alo + (size_t)8 * 1024 * 1024;
  short* Blo = Bhi + (size_t)8 * 1024 * 1024;
  float* bias = (float*)(Blo + (size_t)8 * 1024 * 1024);

  convert_kernel<<<4096, 256, 0, stream>>>(x, h1,
      W_ix, W_fx, W_ox, W_cx, W_ih, W_fh, W_oh, W_ch,
      b_ix, b_fx, b_ox, b_cx, b_ih, b_fh, b_oh, b_ch,
      Ahi, Alo, Bhi, Blo, bias);

  gemm_fused_kernel<<<1024, 256, 0, stream>>>(Ahi, Alo, Bhi, Blo, bias, c1, (float*)d_out);
}

// Round 5
// 298.309 us; speedup vs baseline: 1.3210x; 1.1075x over previous
//
#include <hip/hip_runtime.h>

// LSTM cell: gates = [x|h] @ [Wx|Wh]^T + b -> sigmoid/tanh elementwise.
// Round 3 design (resubmit x2; broker timeouts R3/R4 — never benched):
//   2-term hi/lo split (hh + h*lo(B); dropped lo(A)*hi(B) — accuracy gamble),
//   gate-within-wave interleave n' = (j>>4)*64 + gate*16 + (j&15) so the
//   epilogue runs fully in-register (no LDS gates tile), LDS 48KB -> 3 blocks/CU.

typedef __attribute__((ext_vector_type(4))) float  f32x4;
typedef __attribute__((ext_vector_type(8))) __bf16 bf16x8;
typedef __attribute__((ext_vector_type(8))) short  s16x8;

#define HID    1024
#define BATCH  4096
#define KDIM   2048
#define PANEL_STRIDE (128 * KDIM)   // shorts per 128-row panel plane
#define KT_STRIDE    4096           // shorts per (panel,kt) chunk: 4 g * 128 r * 8 e

// ---------------- fp32 <-> bf16 (round-to-nearest-even) ----------------
__device__ __forceinline__ unsigned short f2bf(float f) {
  unsigned u = __builtin_bit_cast(unsigned, f);
  u += 0x7FFFu + ((u >> 16) & 1u);
  return (unsigned short)(u >> 16);
}
__device__ __forceinline__ float bf2f(unsigned short s) {
  return __builtin_bit_cast(float, (unsigned)s << 16);
}

// ---------------- 1) convert: fp32 -> plane-tiled bf16 (A: hi; B: hi+lo) ----------------
// ws element (panel p, kt, g, r, e) <=> matrix (row = p*128+r, k = kt*32 + g*8 + e)
// B row n' = (j>>4)*64 + gate*16 + (j&15)  =>  j = (n'>>6)*16 + (n'&15), gate = (n'>>4)&3
__global__ void convert_kernel(
    const float* __restrict__ x,   const float* __restrict__ h,
    const float* __restrict__ Wix, const float* __restrict__ Wfx,
    const float* __restrict__ Wox, const float* __restrict__ Wcx,
    const float* __restrict__ Wih, const float* __restrict__ Wfh,
    const float* __restrict__ Woh, const float* __restrict__ Wch,
    const float* __restrict__ bix, const float* __restrict__ bfx,
    const float* __restrict__ box, const float* __restrict__ bcx,
    const float* __restrict__ bih, const float* __restrict__ bfh,
    const float* __restrict__ boh, const float* __restrict__ bch,
    short* __restrict__ Ahi, short* __restrict__ Bhi, short* __restrict__ Blo,
    float* __restrict__ bias)
{
  const int bid = blockIdx.x;
  const int t   = threadIdx.x;
  const int r   = t >> 1;
  const int kh  = t & 1;
  const bool isA = bid < 2048;
  const int pb = isA ? bid : (bid - 2048);
  const int p  = pb >> 6;
  const int kt = pb & 63;
  const int kk = kt * 32 + kh * 16;   // 16-aligned, never straddles the x|h boundary

  const float* srow;
  if (isA) {
    const int m = p * 128 + r;
    srow = (kk < 1024) ? (x + (size_t)m * 1024 + kk)
                       : (h + (size_t)m * 1024 + (kk - 1024));
  } else {
    const int np = p * 128 + r;
    const int j = ((np >> 6) << 4) + (np & 15);
    const int gate = (np >> 4) & 3;
    const float* wx = (gate == 0) ? Wix : (gate == 1) ? Wfx : (gate == 2) ? Wox : Wcx;
    const float* wh = (gate == 0) ? Wih : (gate == 1) ? Wfh : (gate == 2) ? Woh : Wch;
    srow = (kk < 1024) ? (wx + (size_t)j * 1024 + kk)
                       : (wh + (size_t)j * 1024 + (kk - 1024));
    if (kt == 0 && t < 128) {          // combined bias in n' order
      const int np2 = p * 128 + t;
      const int j2 = ((np2 >> 6) << 4) + (np2 & 15);
      const int g2 = (np2 >> 4) & 3;
      const float* bx  = (g2 == 0) ? bix : (g2 == 1) ? bfx : (g2 == 2) ? box : bcx;
      const float* bh2 = (g2 == 0) ? bih : (g2 == 1) ? bfh : (g2 == 2) ? boh : bch;
      bias[np2] = bx[j2] + bh2[j2];
    }
  }
  f32x4 v0 = ((const f32x4*)srow)[0];
  f32x4 v1 = ((const f32x4*)srow)[1];
  f32x4 v2 = ((const f32x4*)srow)[2];
  f32x4 v3 = ((const f32x4*)srow)[3];
  s16x8 h0, l0, h1, l1;
  #pragma unroll
  for (int c = 0; c < 8; ++c) {
    float f0 = (c < 4) ? v0[c & 3] : v1[c & 3];
    unsigned short a = f2bf(f0);
    h0[c] = (short)a; l0[c] = (short)f2bf(f0 - bf2f(a));
    float f1 = (c < 4) ? v2[c & 3] : v3[c & 3];
    unsigned short b = f2bf(f1);
    h1[c] = (short)b; l1[c] = (short)f2bf(f1 - bf2f(b));
  }
  const size_t base = ((size_t)p * 64 + kt) * KT_STRIDE + (size_t)(kh * 2) * 1024 + (size_t)r * 8;
  if (isA) {
    *(s16x8*)(Ahi + base) = h0; *(s16x8*)(Ahi + base + 1024) = h1;
  } else {
    *(s16x8*)(Bhi + base) = h0; *(s16x8*)(Bhi + base + 1024) = h1;
    *(s16x8*)(Blo + base) = l0; *(s16x8*)(Blo + base + 1024) = l1;
  }
}

// ---------------- 2) fused GEMM + in-register LSTM epilogue ----------------
#define GLD16(SRC, DST) \
  __builtin_amdgcn_global_load_lds((const __attribute__((address_space(1))) void*)(SRC), \
                                   (__attribute__((address_space(3))) void*)(DST), 16, 0, 0)

__device__ __forceinline__ float sigmoid_f(float v) { return 1.f / (1.f + __expf(-v)); }
__device__ __forceinline__ float tanh_f(float v) {
  float t = __expf(-2.f * fabsf(v));
  float r = (1.f - t) / (1.f + t);
  return copysignf(r, v);
}

__global__ __launch_bounds__(256, 3) void gemm_fused_kernel(
    const short* __restrict__ Ahi,
    const short* __restrict__ Bhi, const short* __restrict__ Blo,
    const float* __restrict__ bias, const float* __restrict__ c1,
    float* __restrict__ out)
{
  // LDS: 2 buffers x 3 planes (Ahi|Bhi|Blo) x 4096 shorts = 48 KB -> 3 blocks/CU
  __shared__ __align__(16) short sA[2 * 3 * 4096];

  const int tid = threadIdx.x, wave = tid >> 6, lane = tid & 63;
  int bid = blockIdx.x;
  bid = (bid & 7) * 128 + (bid >> 3);          // XCD-aware swizzle (1024 % 8 == 0)
  const int by = bid >> 5, bx = bid & 31;
  const int m0 = by * 128, n0 = bx * 128;
  const int wr = (wave >> 1) * 64, wc = (wave & 1) * 64;

  const short* pAh = Ahi + (size_t)by * PANEL_STRIDE;
  const short* pBh = Bhi + (size_t)bx * PANEL_STRIDE;
  const short* pBl = Blo + (size_t)bx * PANEL_STRIDE;

  f32x4 acc[4][4];
  #pragma unroll
  for (int i = 0; i < 4; ++i)
    #pragma unroll
    for (int j = 0; j < 4; ++j)
      acc[i][j] = (f32x4){0.f, 0.f, 0.f, 0.f};

  const int c0   = wave * 2;     // this wave's 2 staging chunks
  const int loff = lane * 8;     // 16B per lane within chunk

  #define STAGE(BUF, KT) do {                                            \
    const size_t koff = (size_t)(KT) * KT_STRIDE;                        \
    const int sb_ = (BUF) * 12288;                                       \
    _Pragma("unroll")                                                    \
    for (int i_ = 0; i_ < 2; ++i_) {                                     \
      const int c_ = c0 + i_;                                            \
      GLD16(pAh + koff + c_ * 512 + loff, &sA[sb_ + c_ * 512]);          \
      GLD16(pBh + koff + c_ * 512 + loff, &sA[sb_ + 4096 + c_ * 512]);   \
      GLD16(pBl + koff + c_ * 512 + loff, &sA[sb_ + 8192 + c_ * 512]);   \
    }                                                                    \
  } while (0)

  STAGE(0, 0);
  __syncthreads();

  const int g = lane >> 4, frow = lane & 15;
  for (int kt = 0; kt < 64; ++kt) {
    const int cur = kt & 1;
    if (kt < 63) STAGE(cur ^ 1, kt + 1);   // prefetch overlaps this tile's MFMA
    const int sb = cur * 12288;
    bf16x8 ah[4], bh[4], bl[4];
    #pragma unroll
    for (int f = 0; f < 4; ++f) {
      const int ra = g * 1024 + (wr + f * 16 + frow) * 8;   // plane layout: conflict-free
      ah[f] = *(const bf16x8*)&sA[sb + ra];
      const int rb = g * 1024 + (wc + f * 16 + frow) * 8;
      bh[f] = *(const bf16x8*)&sA[sb + 4096 + rb];
      bl[f] = *(const bf16x8*)&sA[sb + 8192 + rb];
    }
    #pragma unroll
    for (int fm = 0; fm < 4; ++fm)
      #pragma unroll
      for (int fn = 0; fn < 4; ++fn) {
        acc[fm][fn] = __builtin_amdgcn_mfma_f32_16x16x32_bf16(ah[fm], bh[fn], acc[fm][fn], 0, 0, 0);
        acc[fm][fn] = __builtin_amdgcn_mfma_f32_16x16x32_bf16(ah[fm], bl[fn], acc[fm][fn], 0, 0, 0);
      }
    __syncthreads();
  }

  // ---- in-register epilogue: lane's 4 fn-columns are gates {i,f,o,c} of one j ----
  // C frag layout: row = wr + (lane>>4)*4 + rr + fm*16, col = wc + fn*16 + (lane&15)
  const int l15 = lane & 15;
  const int j   = (bx * 32) + ((wc >> 6) << 4) + l15;
  const float bv0 = bias[n0 + wc +  0 + l15];
  const float bv1 = bias[n0 + wc + 16 + l15];
  const float bv2 = bias[n0 + wc + 32 + l15];
  const float bv3 = bias[n0 + wc + 48 + l15];
  const int row0 = m0 + wr + ((lane >> 4) << 2);
  #pragma unroll
  for (int fm = 0; fm < 4; ++fm)
    #pragma unroll
    for (int rr = 0; rr < 4; ++rr) {
      const int m = row0 + fm * 16 + rr;
      const float I  = sigmoid_f(acc[fm][0][rr] + bv0);
      const float F  = sigmoid_f(acc[fm][1][rr] + bv1);
      const float O  = sigmoid_f(acc[fm][2][rr] + bv2);
      const float Ct = tanh_f(acc[fm][3][rr] + bv3);
      const float cc = F * c1[(size_t)m * HID + j] + I * Ct;
      out[(size_t)m * HID + j]                       = O * tanh_f(cc);  // h
      out[(size_t)BATCH * HID + (size_t)m * HID + j] = cc;              // c
    }
  #undef STAGE
}

// ---------------- launch ----------------
extern "C" void kernel_launch(void* const* d_in, const int* in_sizes, int n_in,
                              void* d_out, int out_size, void* d_ws, size_t ws_size,
                              hipStream_t stream) {
  const float* x    = (const float*)d_in[0];
  const float* h1   = (const float*)d_in[1];
  const float* c1   = (const float*)d_in[2];
  const float* W_ix = (const float*)d_in[3];  const float* b_ix = (const float*)d_in[4];
  const float* W_ih = (const float*)d_in[5];  const float* b_ih = (const float*)d_in[6];
  const float* W_fx = (const float*)d_in[7];  const float* b_fx = (const float*)d_in[8];
  const float* W_fh = (const float*)d_in[9];  const float* b_fh = (const float*)d_in[10];
  const float* W_ox = (const float*)d_in[11]; const float* b_ox = (const float*)d_in[12];
  const float* W_oh = (const float*)d_in[13]; const float* b_oh = (const float*)d_in[14];
  const float* W_cx = (const float*)d_in[15]; const float* b_cx = (const float*)d_in[16];
  const float* W_ch = (const float*)d_in[17]; const float* b_ch = (const float*)d_in[18];

  // ws: Ahi | Bhi | Blo (16MB each, plane-tiled) | bias_sum (16KB)
  short* Ahi = (short*)d_ws;
  short* Bhi = Ahi + (size_t)8 * 1024 * 1024;
  short* Blo = Bhi + (size_t)8 * 1024 * 1024;
  float* bias = (float*)(Blo + (size_t)8 * 1024 * 1024);

  convert_kernel<<<4096, 256, 0, stream>>>(x, h1,
      W_ix, W_fx, W_ox, W_cx, W_ih, W_fh, W_oh, W_ch,
      b_ix, b_fx, b_ox, b_cx, b_ih, b_fh, b_oh, b_ch,
      Ahi, Bhi, Blo, bias);

  gemm_fused_kernel<<<1024, 256, 0, stream>>>(Ahi, Bhi, Blo, bias, c1, (float*)d_out);
}

// Round 7
// 280.288 us; speedup vs baseline: 1.4059x; 1.0643x over previous
//
#include <hip/hip_runtime.h>

// LSTM cell: gates = [x|h] @ [Wx|Wh]^T + b -> sigmoid/tanh elementwise.
// Round 6 design (resubmit; broker timeout — never benched):
//   8-phase-style counted-vmcnt GEMM (T2+T3+T4+T5 stack):
//   256x256 tile, 512 thr / 8 waves (2Mx4N), BK=32, 3-deep LDS ring (144 KB),
//   raw s_barrier + s_waitcnt vmcnt(6) at K-tile boundaries (never 0 in steady state),
//   4 phases/K-tile x 16 MFMA with setprio(1), staging spread across phases.
// Math unchanged from R5: 2-term hi/lo split (hh + h*lo(B)), plane-tiled ws layout,
// in-register LSTM epilogue via gate interleave n' = (j>>4)*64 + gate*16 + (j&15).

typedef __attribute__((ext_vector_type(4))) float  f32x4;
typedef __attribute__((ext_vector_type(8))) __bf16 bf16x8;
typedef __attribute__((ext_vector_type(8))) short  s16x8;

#define HID    1024
#define BATCH  4096
#define KDIM   2048
#define KT_STRIDE 4096   // shorts per (128-row panel, kt) chunk: 4 g * 128 r * 8 e

// ---------------- fp32 <-> bf16 (round-to-nearest-even) ----------------
__device__ __forceinline__ unsigned short f2bf(float f) {
  unsigned u = __builtin_bit_cast(unsigned, f);
  u += 0x7FFFu + ((u >> 16) & 1u);
  return (unsigned short)(u >> 16);
}
__device__ __forceinline__ float bf2f(unsigned short s) {
  return __builtin_bit_cast(float, (unsigned)s << 16);
}

// ---------------- 1) convert: fp32 -> plane-tiled bf16 (A: hi; B: hi+lo) ----------------
// ws element (panel p, kt, g, r, e) <=> matrix (row = p*128+r, k = kt*32 + g*8 + e)
// B row n' = (j>>4)*64 + gate*16 + (j&15)  =>  j = (n'>>6)*16 + (n'&15), gate = (n'>>4)&3
__global__ void convert_kernel(
    const float* __restrict__ x,   const float* __restrict__ h,
    const float* __restrict__ Wix, const float* __restrict__ Wfx,
    const float* __restrict__ Wox, const float* __restrict__ Wcx,
    const float* __restrict__ Wih, const float* __restrict__ Wfh,
    const float* __restrict__ Woh, const float* __restrict__ Wch,
    const float* __restrict__ bix, const float* __restrict__ bfx,
    const float* __restrict__ box, const float* __restrict__ bcx,
    const float* __restrict__ bih, const float* __restrict__ bfh,
    const float* __restrict__ boh, const float* __restrict__ bch,
    short* __restrict__ Ahi, short* __restrict__ Bhi, short* __restrict__ Blo,
    float* __restrict__ bias)
{
  const int bid = blockIdx.x;
  const int t   = threadIdx.x;
  const int r   = t >> 1;
  const int kh  = t & 1;
  const bool isA = bid < 2048;
  const int pb = isA ? bid : (bid - 2048);
  const int p  = pb >> 6;
  const int kt = pb & 63;
  const int kk = kt * 32 + kh * 16;   // 16-aligned, never straddles the x|h boundary

  const float* srow;
  if (isA) {
    const int m = p * 128 + r;
    srow = (kk < 1024) ? (x + (size_t)m * 1024 + kk)
                       : (h + (size_t)m * 1024 + (kk - 1024));
  } else {
    const int np = p * 128 + r;
    const int j = ((np >> 6) << 4) + (np & 15);
    const int gate = (np >> 4) & 3;
    const float* wx = (gate == 0) ? Wix : (gate == 1) ? Wfx : (gate == 2) ? Wox : Wcx;
    const float* wh = (gate == 0) ? Wih : (gate == 1) ? Wfh : (gate == 2) ? Woh : Wch;
    srow = (kk < 1024) ? (wx + (size_t)j * 1024 + kk)
                       : (wh + (size_t)j * 1024 + (kk - 1024));
    if (kt == 0 && t < 128) {          // combined bias in n' order
      const int np2 = p * 128 + t;
      const int j2 = ((np2 >> 6) << 4) + (np2 & 15);
      const int g2 = (np2 >> 4) & 3;
      const float* bx  = (g2 == 0) ? bix : (g2 == 1) ? bfx : (g2 == 2) ? box : bcx;
      const float* bh2 = (g2 == 0) ? bih : (g2 == 1) ? bfh : (g2 == 2) ? boh : bch;
      bias[np2] = bx[j2] + bh2[j2];
    }
  }
  f32x4 v0 = ((const f32x4*)srow)[0];
  f32x4 v1 = ((const f32x4*)srow)[1];
  f32x4 v2 = ((const f32x4*)srow)[2];
  f32x4 v3 = ((const f32x4*)srow)[3];
  s16x8 h0, l0, h1, l1;
  #pragma unroll
  for (int c = 0; c < 8; ++c) {
    float f0 = (c < 4) ? v0[c & 3] : v1[c & 3];
    unsigned short a = f2bf(f0);
    h0[c] = (short)a; l0[c] = (short)f2bf(f0 - bf2f(a));
    float f1 = (c < 4) ? v2[c & 3] : v3[c & 3];
    unsigned short b = f2bf(f1);
    h1[c] = (short)b; l1[c] = (short)f2bf(f1 - bf2f(b));
  }
  const size_t base = ((size_t)p * 64 + kt) * KT_STRIDE + (size_t)(kh * 2) * 1024 + (size_t)r * 8;
  if (isA) {
    *(s16x8*)(Ahi + base) = h0; *(s16x8*)(Ahi + base + 1024) = h1;
  } else {
    *(s16x8*)(Bhi + base) = h0; *(s16x8*)(Bhi + base + 1024) = h1;
    *(s16x8*)(Blo + base) = l0; *(s16x8*)(Blo + base + 1024) = l1;
  }
}

// ---------------- 2) fused GEMM + in-register LSTM epilogue (8-phase style) ----------------
#define GLD16(SRC, DST) \
  __builtin_amdgcn_global_load_lds((const __attribute__((address_space(1))) void*)(SRC), \
                                   (__attribute__((address_space(3))) void*)(DST), 16, 0, 0)

__device__ __forceinline__ float sigmoid_f(float v) { return 1.f / (1.f + __expf(-v)); }
__device__ __forceinline__ float tanh_f(float v) {
  float t = __expf(-2.f * fabsf(v));
  float r = (1.f - t) / (1.f + t);
  return copysignf(r, v);
}

__global__ __launch_bounds__(512, 2) void gemm_fused_kernel(
    const short* __restrict__ Ahi,
    const short* __restrict__ Bhi, const short* __restrict__ Blo,
    const float* __restrict__ bias, const float* __restrict__ c1,
    float* __restrict__ out)
{
  // 3-deep ring of K-tile buffers; each buffer: A[2 chunks] | Bhi[2] | Blo[2],
  // chunk = 4096 shorts in plane layout [4 g][128 r][8 e]. 3 * 48 KB = 144 KB.
  __shared__ __align__(16) short sA[3 * 24576];

  const int tid = threadIdx.x, wave = tid >> 6, lane = tid & 63;
  int bid = blockIdx.x;
  bid = (bid & 7) * 32 + (bid >> 3);         // XCD-aware swizzle (256 % 8 == 0)
  const int by = bid >> 4, bx = bid & 15;    // 16 x 16 tile grid
  const int wm = wave >> 2, wn = wave & 3;   // 2M x 4N waves
  const int g = lane >> 4, frow = lane & 15;
  const int loff = lane * 8;

  f32x4 acc[8][4];
  #pragma unroll
  for (int i = 0; i < 8; ++i)
    #pragma unroll
    for (int j = 0; j < 4; ++j) acc[i][j] = (f32x4){0.f, 0.f, 0.f, 0.f};

  // staging: 48 GLD16 per K-tile, flat idx = wave*6 + i:
  //   idx 0-15 A (chunk idx>>3 &1, seg idx&7), 16-31 Bhi, 32-47 Blo
#define STAGE1(I_, KT2, SBUF) do {                                                      \
    const int idx_ = wave * 6 + (I_);                                                   \
    const int pl_ = idx_ >> 4, c_ = (idx_ >> 3) & 1, s_ = idx_ & 7;                     \
    const short* gsrc_; int ldst_;                                                      \
    if (pl_ == 0)      { gsrc_ = Ahi + (size_t)((2*by + c_) * 64 + (KT2)) * KT_STRIDE;  \
                         ldst_ = (SBUF) + c_ * 4096; }                                  \
    else if (pl_ == 1) { gsrc_ = Bhi + (size_t)((2*bx + c_) * 64 + (KT2)) * KT_STRIDE;  \
                         ldst_ = (SBUF) + 8192 + c_ * 4096; }                           \
    else               { gsrc_ = Blo + (size_t)((2*bx + c_) * 64 + (KT2)) * KT_STRIDE;  \
                         ldst_ = (SBUF) + 16384 + c_ * 4096; }                          \
    GLD16(gsrc_ + s_ * 512 + loff, &sA[ldst_ + s_ * 512]);                              \
  } while (0)

#define MFMA_Q(FM0, FN0)                                                                 \
    _Pragma("unroll")                                                                    \
    for (int f_ = 0; f_ < 4; ++f_) {                                                     \
      acc[(FM0)+f_][(FN0)  ] = __builtin_amdgcn_mfma_f32_16x16x32_bf16(ah[f_], bh[0], acc[(FM0)+f_][(FN0)  ], 0, 0, 0); \
      acc[(FM0)+f_][(FN0)  ] = __builtin_amdgcn_mfma_f32_16x16x32_bf16(ah[f_], bl[0], acc[(FM0)+f_][(FN0)  ], 0, 0, 0); \
      acc[(FM0)+f_][(FN0)+1] = __builtin_amdgcn_mfma_f32_16x16x32_bf16(ah[f_], bh[1], acc[(FM0)+f_][(FN0)+1], 0, 0, 0); \
      acc[(FM0)+f_][(FN0)+1] = __builtin_amdgcn_mfma_f32_16x16x32_bf16(ah[f_], bl[1], acc[(FM0)+f_][(FN0)+1], 0, 0, 0); \
    }

  // prologue: tiles 0 -> buf0, 1 -> buf1 (12 loads/wave in flight)
  #pragma unroll
  for (int i = 0; i < 6; ++i) STAGE1(i, 0, 0);
  #pragma unroll
  for (int i = 0; i < 6; ++i) STAGE1(i, 1, 24576);

  for (int kt = 0; kt < 64; ++kt) {
    // K-tile boundary: wait own 6 loads of tile kt (leave kt+1's 6 in flight), sync.
    if (kt < 62) asm volatile("s_waitcnt vmcnt(6)" ::: "memory");
    else         asm volatile("s_waitcnt vmcnt(0)" ::: "memory");
    __builtin_amdgcn_s_barrier();

    const int sb  = (kt % 3) * 24576;
    const int sb2 = ((kt + 2) % 3) * 24576;
    const bool st = (kt < 62);
    const int abase  = sb + wm * 4096 + g * 1024 + frow * 8;
    const int bboff  = (wn >> 1) * 4096 + g * 1024 + ((wn & 1) * 64 + frow) * 8;
    const int bhbase = sb + 8192  + bboff;
    const int blbase = sb + 16384 + bboff;

    bf16x8 ah[4], bh[2], bl[2];

    // ---- q0: fm 0-3 x fn 0-1 ----
    #pragma unroll
    for (int f_ = 0; f_ < 4; ++f_) ah[f_] = *(const bf16x8*)&sA[abase + f_ * 128];
    bh[0] = *(const bf16x8*)&sA[bhbase];       bh[1] = *(const bf16x8*)&sA[bhbase + 128];
    bl[0] = *(const bf16x8*)&sA[blbase];       bl[1] = *(const bf16x8*)&sA[blbase + 128];
    if (st) { STAGE1(0, kt + 2, sb2); STAGE1(1, kt + 2, sb2); }
    __builtin_amdgcn_s_barrier();
    __builtin_amdgcn_s_setprio(1);
    MFMA_Q(0, 0)
    __builtin_amdgcn_s_setprio(0);
    __builtin_amdgcn_s_barrier();

    // ---- q1: fm 0-3 x fn 2-3 (reuse ah) ----
    bh[0] = *(const bf16x8*)&sA[bhbase + 256]; bh[1] = *(const bf16x8*)&sA[bhbase + 384];
    bl[0] = *(const bf16x8*)&sA[blbase + 256]; bl[1] = *(const bf16x8*)&sA[blbase + 384];
    if (st) { STAGE1(2, kt + 2, sb2); STAGE1(3, kt + 2, sb2); }
    __builtin_amdgcn_s_barrier();
    __builtin_amdgcn_s_setprio(1);
    MFMA_Q(0, 2)
    __builtin_amdgcn_s_setprio(0);
    __builtin_amdgcn_s_barrier();

    // ---- q2: fm 4-7 x fn 2-3 (reuse bh/bl) ----
    #pragma unroll
    for (int f_ = 0; f_ < 4; ++f_) ah[f_] = *(const bf16x8*)&sA[abase + 512 + f_ * 128];
    if (st) { STAGE1(4, kt + 2, sb2); STAGE1(5, kt + 2, sb2); }
    __builtin_amdgcn_s_barrier();
    __builtin_amdgcn_s_setprio(1);
    MFMA_Q(4, 2)
    __builtin_amdgcn_s_setprio(0);
    __builtin_amdgcn_s_barrier();

    // ---- q3: fm 4-7 x fn 0-1 (reuse ah) ----
    bh[0] = *(const bf16x8*)&sA[bhbase];       bh[1] = *(const bf16x8*)&sA[bhbase + 128];
    bl[0] = *(const bf16x8*)&sA[blbase];       bl[1] = *(const bf16x8*)&sA[blbase + 128];
    __builtin_amdgcn_s_barrier();
    __builtin_amdgcn_s_setprio(1);
    MFMA_Q(4, 0)
    __builtin_amdgcn_s_setprio(0);
    // no trailing barrier: next iteration's top barrier covers it
  }

  // ---- in-register epilogue: lane's 4 fn-columns are gates {i,f,o,c} of one j ----
  // C frag layout: row = wm*128 + fm*16 + g*4 + rr, col = wn*64 + fn*16 + frow
  const int n0 = bx * 256;
  const int j  = bx * 64 + wn * 16 + frow;
  const float bv0 = bias[n0 + wn * 64 +  0 + frow];
  const float bv1 = bias[n0 + wn * 64 + 16 + frow];
  const float bv2 = bias[n0 + wn * 64 + 32 + frow];
  const float bv3 = bias[n0 + wn * 64 + 48 + frow];
  const int row0 = by * 256 + wm * 128 + g * 4;
  #pragma unroll
  for (int fm = 0; fm < 8; ++fm)
    #pragma unroll
    for (int rr = 0; rr < 4; ++rr) {
      const int m = row0 + fm * 16 + rr;
      const float I  = sigmoid_f(acc[fm][0][rr] + bv0);
      const float F  = sigmoid_f(acc[fm][1][rr] + bv1);
      const float O  = sigmoid_f(acc[fm][2][rr] + bv2);
      const float Ct = tanh_f(acc[fm][3][rr] + bv3);
      const float cc = F * c1[(size_t)m * HID + j] + I * Ct;
      out[(size_t)m * HID + j]                       = O * tanh_f(cc);  // h
      out[(size_t)BATCH * HID + (size_t)m * HID + j] = cc;              // c
    }
  #undef STAGE1
  #undef MFMA_Q
}

// ---------------- launch ----------------
extern "C" void kernel_launch(void* const* d_in, const int* in_sizes, int n_in,
                              void* d_out, int out_size, void* d_ws, size_t ws_size,
                              hipStream_t stream) {
  const float* x    = (const float*)d_in[0];
  const float* h1   = (const float*)d_in[1];
  const float* c1   = (const float*)d_in[2];
  const float* W_ix = (const float*)d_in[3];  const float* b_ix = (const float*)d_in[4];
  const float* W_ih = (const float*)d_in[5];  const float* b_ih = (const float*)d_in[6];
  const float* W_fx = (const float*)d_in[7];  const float* b_fx = (const float*)d_in[8];
  const float* W_fh = (const float*)d_in[9];  const float* b_fh = (const float*)d_in[10];
  const float* W_ox = (const float*)d_in[11]; const float* b_ox = (const float*)d_in[12];
  const float* W_oh = (const float*)d_in[13]; const float* b_oh = (const float*)d_in[14];
  const float* W_cx = (const float*)d_in[15]; const float* b_cx = (const float*)d_in[16];
  const float* W_ch = (const float*)d_in[17]; const float* b_ch = (const float*)d_in[18];

  // ws: Ahi | Bhi | Blo (16MB each, plane-tiled) | bias_sum (16KB)
  short* Ahi = (short*)d_ws;
  short* Bhi = Ahi + (size_t)8 * 1024 * 1024;
  short* Blo = Bhi + (size_t)8 * 1024 * 1024;
  float* bias = (float*)(Blo + (size_t)8 * 1024 * 1024);

  convert_kernel<<<4096, 256, 0, stream>>>(x, h1,
      W_ix, W_fx, W_ox, W_cx, W_ih, W_fh, W_oh, W_ch,
      b_ix, b_fx, b_ox, b_cx, b_ih, b_fh, b_oh, b_ch,
      Ahi, Bhi, Blo, bias);

  gemm_fused_kernel<<<256, 512, 0, stream>>>(Ahi, Bhi, Blo, bias, c1, (float*)d_out);
}